// Round 5
// baseline (273.255 us; speedup 1.0000x reference)
//
#include <hip/hip_runtime.h>

#define SS 1024
#define BB 4096
#define HH 8
#define XSTRIDE (BB * HH)   // floats per timestep slice
#define NG 256              // groups of 4 steps

typedef float f32x2 __attribute__((ext_vector_type(2)));

// DPP cross-lane (VALU pipe): xor1/xor2 via quad_perm, xor7 via row_half_mirror.
__device__ __forceinline__ int dpp_x1(int v) {
    return __builtin_amdgcn_mov_dpp(v, 0xB1, 0xF, 0xF, true);   // quad_perm [1,0,3,2]
}
__device__ __forceinline__ int dpp_x2(int v) {
    return __builtin_amdgcn_mov_dpp(v, 0x4E, 0xF, 0xF, true);   // quad_perm [2,3,0,1]
}
__device__ __forceinline__ int dpp_x7(int v) {
    return __builtin_amdgcn_mov_dpp(v, 0x141, 0xF, 0xF, true);  // row_half_mirror
}

// Butterfly register m holds h[j ^ MK[m]]; h-side weights pre-permuted to match.
__device__ __constant__ int MK_[8] = {0, 1, 2, 3, 7, 6, 5, 4};

// X-phase (one chain C, one step U): input-side pre-activations.
// Weights/biases are PRE-SCALED: r/z rows by -log2(e) (sigmoid -> rcp(1+exp2(acc))),
// n rows by +2*log2(e) (tanh(y) -> 1 - 2*rcp(1+exp2(2*log2e*y))).
#define XSTEP(C, X0, X1, U) do {                                                       \
    f32x2 a0_ = {(X0).x, (X0).y}, a1_ = {(X0).z, (X0).w};                              \
    f32x2 a2_ = {(X1).x, (X1).y}, a3_ = {(X1).z, (X1).w};                              \
    f32x2 sr_ = {bias_r, 0.0f}, sz_ = {bias_z, 0.0f}, sn_ = {bni_s, 0.0f};             \
    sr_ = __builtin_elementwise_fma(a0_, wri[0], sr_);                                 \
    sz_ = __builtin_elementwise_fma(a0_, wzi[0], sz_);                                 \
    sn_ = __builtin_elementwise_fma(a0_, wni[0], sn_);                                 \
    sr_ = __builtin_elementwise_fma(a1_, wri[1], sr_);                                 \
    sz_ = __builtin_elementwise_fma(a1_, wzi[1], sz_);                                 \
    sn_ = __builtin_elementwise_fma(a1_, wni[1], sn_);                                 \
    sr_ = __builtin_elementwise_fma(a2_, wri[2], sr_);                                 \
    sz_ = __builtin_elementwise_fma(a2_, wzi[2], sz_);                                 \
    sn_ = __builtin_elementwise_fma(a2_, wni[2], sn_);                                 \
    sr_ = __builtin_elementwise_fma(a3_, wri[3], sr_);                                 \
    sz_ = __builtin_elementwise_fma(a3_, wzi[3], sz_);                                 \
    sn_ = __builtin_elementwise_fma(a3_, wni[3], sn_);                                 \
    C##xr[U] = sr_.x + sr_.y; C##xz[U] = sz_.x + sz_.y; C##xn[U] = sn_.x + sn_.y;      \
} while (0)

// DPP butterfly refresh of one chain's hv[] from its new h.
#define BFLY(C) do {                                                                   \
    const int hb_ = __float_as_int(C##h);                                              \
    const int t1_ = dpp_x1(hb_);                                                       \
    const int t2_ = dpp_x2(hb_);                                                       \
    const int t3_ = dpp_x2(t1_);                                                       \
    const int t4_ = dpp_x7(hb_);                                                       \
    const int t5_ = dpp_x7(t1_);                                                       \
    const int t6_ = dpp_x7(t2_);                                                       \
    const int t7_ = dpp_x7(t3_);                                                       \
    C##hv[0] = (f32x2){C##h, __int_as_float(t1_)};                                     \
    C##hv[1] = (f32x2){__int_as_float(t2_), __int_as_float(t3_)};                      \
    C##hv[2] = (f32x2){__int_as_float(t4_), __int_as_float(t5_)};                      \
    C##hv[3] = (f32x2){__int_as_float(t6_), __int_as_float(t7_)};                      \
} while (0)

// R-phase for BOTH chains, hand-interleaved: chain Q's independent ops fill
// chain P's dependent-chain stalls (in-order wave, 1 wave/SIMD -> static ILP
// is the only latency hiding available).
#define RSTEP2(U, SIDX) do {                                                           \
    f32x2 Pr2 = {Pxr[U], 0.0f}, Qr2 = {Qxr[U], 0.0f};                                  \
    f32x2 Pz2 = {Pxz[U], 0.0f}, Qz2 = {Qxz[U], 0.0f};                                  \
    f32x2 Pn2 = {bnh_s, 0.0f},  Qn2 = {bnh_s, 0.0f};                                   \
    _Pragma("unroll")                                                                  \
    for (int p_ = 0; p_ < 4; ++p_) {                                                   \
        Pr2 = __builtin_elementwise_fma(Phv[p_], wrh[p_], Pr2);                        \
        Qr2 = __builtin_elementwise_fma(Qhv[p_], wrh[p_], Qr2);                        \
        Pz2 = __builtin_elementwise_fma(Phv[p_], wzh[p_], Pz2);                        \
        Qz2 = __builtin_elementwise_fma(Qhv[p_], wzh[p_], Qz2);                        \
        Pn2 = __builtin_elementwise_fma(Phv[p_], wnh[p_], Pn2);                        \
        Qn2 = __builtin_elementwise_fma(Qhv[p_], wnh[p_], Qn2);                        \
    }                                                                                  \
    const float PEr = __builtin_amdgcn_exp2f(Pr2.x + Pr2.y);                           \
    const float QEr = __builtin_amdgcn_exp2f(Qr2.x + Qr2.y);                           \
    const float PEz = __builtin_amdgcn_exp2f(Pz2.x + Pz2.y);                           \
    const float QEz = __builtin_amdgcn_exp2f(Qz2.x + Qz2.y);                           \
    const float Pr_ = __builtin_amdgcn_rcpf(1.0f + PEr);                               \
    const float Qr_ = __builtin_amdgcn_rcpf(1.0f + QEr);                               \
    const float Pz_ = __builtin_amdgcn_rcpf(1.0f + PEz);                               \
    const float Qz_ = __builtin_amdgcn_rcpf(1.0f + QEz);                               \
    const float PEn = __builtin_amdgcn_exp2f(fmaf(Pr_, Pn2.x + Pn2.y, Pxn[U]));        \
    const float QEn = __builtin_amdgcn_exp2f(fmaf(Qr_, Qn2.x + Qn2.y, Qxn[U]));        \
    const float Pn_ = fmaf(-2.0f, __builtin_amdgcn_rcpf(1.0f + PEn), 1.0f);            \
    const float Qn_ = fmaf(-2.0f, __builtin_amdgcn_rcpf(1.0f + QEn), 1.0f);            \
    Ph = Pn_ + Pz_ * (Ph - Pn_);                                                       \
    Qh = Qn_ + Qz_ * (Qh - Qn_);                                                       \
    BFLY(P);                                                                           \
    BFLY(Q);                                                                           \
    Pop[(size_t)(SIDX) * XSTRIDE] = Ph;                                                \
    Qop[(size_t)(SIDX) * XSTRIDE] = Qh;                                                \
} while (0)

// Load one 4-step group of x for one chain into an 8x float4 register buffer.
#define LOADG(DST, XPTR, GRP) do {                                                     \
    const float* bp_ = (XPTR) + (size_t)(GRP) * 4 * XSTRIDE;                           \
    _Pragma("unroll")                                                                  \
    for (int u_ = 0; u_ < 4; ++u_) {                                                   \
        const float* p_ = bp_ + (size_t)u_ * XSTRIDE;                                  \
        DST[2 * u_]     = *(const float4*)p_;                                          \
        DST[2 * u_ + 1] = *(const float4*)(p_ + 4);                                    \
    }                                                                                  \
} while (0)

// 8 lanes per batch element; TWO batch groups (chains P,Q) per wave -> 16
// batches/wave, 256 blocks of 1 wave.
__global__ __launch_bounds__(64, 1) void gru_kernel(
    const float* __restrict__ x,
    const float* __restrict__ w_ih,
    const float* __restrict__ w_hh,
    const float* __restrict__ b_ih,
    const float* __restrict__ b_hh,
    float* __restrict__ out)
{
    const int lane = threadIdx.x;
    const int j = lane & 7;
    const int bgP = (blockIdx.x << 4) + (lane >> 3);
    const int bgQ = bgP + 8;

    const float SR = -1.4426950408889634f;   // -log2(e): r/z sigmoid scale
    const float SN = 2.8853900817779268f;    // 2*log2(e): n tanh scale

    // x-side weights, pre-scaled
    f32x2 wri[4], wzi[4], wni[4];
    #pragma unroll
    for (int p = 0; p < 4; ++p) {
        wri[p] = (f32x2){SR * w_ih[j * 8 + 2 * p],        SR * w_ih[j * 8 + 2 * p + 1]};
        wzi[p] = (f32x2){SR * w_ih[(8 + j) * 8 + 2 * p],  SR * w_ih[(8 + j) * 8 + 2 * p + 1]};
        wni[p] = (f32x2){SN * w_ih[(16 + j) * 8 + 2 * p], SN * w_ih[(16 + j) * 8 + 2 * p + 1]};
    }
    // h-side weights: butterfly-permuted columns j ^ MK[m], pre-scaled
    f32x2 wrh[4], wzh[4], wnh[4];
    #pragma unroll
    for (int p = 0; p < 4; ++p) {
        const int c0 = j ^ MK_[2 * p], c1 = j ^ MK_[2 * p + 1];
        wrh[p] = (f32x2){SR * w_hh[j * 8 + c0],        SR * w_hh[j * 8 + c1]};
        wzh[p] = (f32x2){SR * w_hh[(8 + j) * 8 + c0],  SR * w_hh[(8 + j) * 8 + c1]};
        wnh[p] = (f32x2){SN * w_hh[(16 + j) * 8 + c0], SN * w_hh[(16 + j) * 8 + c1]};
    }
    const float bias_r = SR * (b_ih[j] + b_hh[j]);
    const float bias_z = SR * (b_ih[8 + j] + b_hh[8 + j]);
    const float bni_s  = SN * b_ih[16 + j];
    const float bnh_s  = SN * b_hh[16 + j];

    const float* PxP = x + (size_t)bgP * HH;
    const float* QxP = x + (size_t)bgQ * HH;
    float* Pop = out + (size_t)bgP * HH + j;
    float* Qop = out + (size_t)bgQ * HH + j;
    float* Phl = out + (size_t)SS * BB * HH + (size_t)bgP * HH + j;
    float* Qhl = out + (size_t)SS * BB * HH + (size_t)bgQ * HH + j;

    float4 PxA[8], PxB[8], QxA[8], QxB[8];

    // prologue: group 0 -> A for both chains
    LOADG(PxA, PxP, 0);
    LOADG(QxA, QxP, 0);
    __builtin_amdgcn_sched_barrier(0);

    float Ph = 0.0f, Qh = 0.0f;
    f32x2 Phv[4] = {{0,0},{0,0},{0,0},{0,0}};
    f32x2 Qhv[4] = {{0,0},{0,0},{0,0},{0,0}};
    float Pxr[4], Pxz[4], Pxn[4], Qxr[4], Qxz[4], Qxn[4];

    for (int g = 0; g < NG; g += 2) {
        LOADG(PxB, PxP, g + 1);
        LOADG(QxB, QxP, g + 1);
        __builtin_amdgcn_sched_barrier(0);
        #pragma unroll
        for (int u = 0; u < 4; ++u) { XSTEP(P, PxA[2*u], PxA[2*u+1], u); XSTEP(Q, QxA[2*u], QxA[2*u+1], u); }
        #pragma unroll
        for (int u = 0; u < 4; ++u) RSTEP2(u, g * 4 + u);
        {
            const int ga = (g + 2 < NG) ? (g + 2) : (NG - 1);
            LOADG(PxA, PxP, ga);
            LOADG(QxA, QxP, ga);
        }
        __builtin_amdgcn_sched_barrier(0);
        #pragma unroll
        for (int u = 0; u < 4; ++u) { XSTEP(P, PxB[2*u], PxB[2*u+1], u); XSTEP(Q, QxB[2*u], QxB[2*u+1], u); }
        #pragma unroll
        for (int u = 0; u < 4; ++u) RSTEP2(u, (g + 1) * 4 + u);
    }
    *Phl = Ph;
    *Qhl = Qh;
}

extern "C" void kernel_launch(void* const* d_in, const int* in_sizes, int n_in,
                              void* d_out, int out_size, void* d_ws, size_t ws_size,
                              hipStream_t stream) {
    const float* x    = (const float*)d_in[0];
    const float* w_ih = (const float*)d_in[1];
    const float* w_hh = (const float*)d_in[2];
    const float* b_ih = (const float*)d_in[3];
    const float* b_hh = (const float*)d_in[4];
    float* out = (float*)d_out;
    gru_kernel<<<BB / 16, 64, 0, stream>>>(x, w_ih, w_hh, b_ih, b_hh, out);
}